// Round 15
// baseline (128.131 us; speedup 1.0000x reference)
//
#include <hip/hip_runtime.h>
#include <hip/hip_bf16.h>

// Problem constants
#define B_  2
#define S_  2048
#define D_  1024
#define H_  16
#define DK_ 64
#define BH_ (B_*H_)     // 32
#define M_  (B_*S_)     // 4096

typedef __attribute__((ext_vector_type(8))) short bf16x8;
typedef __attribute__((ext_vector_type(4))) float f32x4;

__device__ inline unsigned short f2bf(float f) {   // manual RNE
    unsigned u = __float_as_uint(f);
    u += 0x7fffu + ((u >> 16) & 1u);
    return (unsigned short)(u >> 16);
}
__device__ inline unsigned short f2bf_hw(float f) {
    __hip_bfloat16 h = __float2bfloat16(f);
    return *reinterpret_cast<unsigned short*>(&h);
}
__device__ inline unsigned packbf2(float lo, float hi) {
    return (unsigned)f2bf_hw(lo) | ((unsigned)f2bf_hw(hi) << 16);
}

// async 16B global->LDS (LDS dest must be linear: uniform base + lane*16)
__device__ inline void gld16(const void* g, void* l) {
    __builtin_amdgcn_global_load_lds(
        (const __attribute__((address_space(1))) unsigned int*)g,
        (__attribute__((address_space(3))) unsigned int*)l, 16, 0, 0);
}

// ---------------- cast fp32 -> bf16 (x) ----------------
__global__ void cast_f32_to_bf16(const float* __restrict__ src,
                                 unsigned short* __restrict__ dst, int n) {
    int i = (blockIdx.x * blockDim.x + threadIdx.x) * 4;
    int stride = gridDim.x * blockDim.x * 4;
    for (int j = i; j < n; j += stride) {
        float4 v = *reinterpret_cast<const float4*>(src + j);
        ushort4 o;
        o.x = f2bf(v.x); o.y = f2bf(v.y); o.z = f2bf(v.z); o.w = f2bf(v.w);
        *reinterpret_cast<ushort4*>(dst + j) = o;
    }
}

// ---------------- 4 weight casts in one launch ----------------
__global__ void cast4_f32_to_bf16(const float* __restrict__ s0, const float* __restrict__ s1,
                                  const float* __restrict__ s2, const float* __restrict__ s3,
                                  unsigned short* __restrict__ d0, unsigned short* __restrict__ d1,
                                  unsigned short* __restrict__ d2, unsigned short* __restrict__ d3) {
    const float* s; unsigned short* d;
    switch (blockIdx.y) {
        case 0: s = s0; d = d0; break;
        case 1: s = s1; d = d1; break;
        case 2: s = s2; d = d2; break;
        default: s = s3; d = d3; break;
    }
    int j = (blockIdx.x * blockDim.x + threadIdx.x) * 4;
    float4 v = *reinterpret_cast<const float4*>(s + j);
    ushort4 o;
    o.x = f2bf(v.x); o.y = f2bf(v.y); o.z = f2bf(v.z); o.w = f2bf(v.w);
    *reinterpret_cast<ushort4*>(d + j) = o;
}

// ---------------- fused QKV projection + RoPE + fragment-major store (v2) --------------
// 128x128 tile, 512 threads (8 waves: wm=wid&3 row-group of 32, wn=wid>>2 col-group of 64).
// TRIPLE-buffered BK=64 K-tiles (96 KB LDS), counted vmcnt(8) (never 0 in main loop),
// raw s_barrier pairs, stage t+3 after the read-barrier.  Loads stay in flight across
// barriers (T4 mechanism, m218: counted-vs-drain0 = +38-73%).
// LDS slot map: issue q, thread tid -> stores A[row=tid>>2][chunk c], c = (((tid&3)<<1)|q)
// ^ (row&7).  Read addr for (r, c): p = c^(r&7); el = (p&1)*4096 + r*32 + (p>>1)*8.
// (8 rows cover 8 distinct 16B slots per 128B bank-cycle -> 2-way max = free.)
// Output layouts (unchanged):
// Q:  Qf[bh][s/16][c=dk/32][lane][e]           lane=(s&15)|((dk>>3)&3)<<4, e=dk&7
// K:  Kf[bh][kv/64][n][c][lane][e]  PERMUTED: row v=kv&63 -> n=(v>>5)*2|((v>>2)&1),
//     slot=((v&31)>>3)*4+(v&3); lane=slot|((dk>>3)&3)<<4.
// V:  Vf[bh][dk/16][kv/32][lane][e]            lane=(dk&15)|((kv>>3)&3)<<4, e=kv&7
#define BMQ 128
#define BNQ 128

__global__ __launch_bounds__(512)
void gemm_qkv(const unsigned short* __restrict__ A, const unsigned short* __restrict__ Wcat,
              unsigned short* __restrict__ Qf, unsigned short* __restrict__ Kf,
              unsigned short* __restrict__ Vf) {
    __shared__ unsigned short As[3][8192];   // 48 KB
    __shared__ unsigned short Bs[3][8192];   // 48 KB
    const int tid  = threadIdx.x;            // 0..511
    const int lane = tid & 63;
    const int wid  = tid >> 6;               // 0..7
    const int wm = wid & 3;                  // row group (32 rows)
    const int wn = wid >> 2;                 // col group (64 cols)
    const int m0 = blockIdx.y * BMQ, n0 = blockIdx.x * BNQ;
    const int g  = lane >> 4, cl = lane & 15;

    f32x4 acc[2][4];
#pragma unroll
    for (int i = 0; i < 2; i++)
#pragma unroll
        for (int j = 0; j < 4; j++) acc[i][j] = f32x4{0.f, 0.f, 0.f, 0.f};

    // staging sources: row = tid>>2 (0..127); two 8-el chunks q=0,1
    const int srow = tid >> 2;
    const unsigned short* Asrc[2];
    const unsigned short* Bsrc[2];
#pragma unroll
    for (int q = 0; q < 2; q++) {
        const int c = (((tid & 3) << 1) | q) ^ (srow & 7);
        Asrc[q] = A    + (long)(m0 + srow) * D_ + c * 8;
        Bsrc[q] = Wcat + (long)(n0 + srow) * D_ + c * 8;
    }

    auto STAGE = [&](int t) {
        unsigned short* Ab = &As[t % 3][0];
        unsigned short* Bb = &Bs[t % 3][0];
        const int k0 = t * 64;
#pragma unroll
        for (int q = 0; q < 2; q++) {
            gld16(Asrc[q] + k0, Ab + q * 4096 + tid * 8);
            gld16(Bsrc[q] + k0, Bb + q * 4096 + tid * 8);
        }
    };

    auto COMPUTE = [&](int bufi) {
        const unsigned short* Ab = &As[bufi][0];
        const unsigned short* Bb = &Bs[bufi][0];
        bf16x8 bfr[4][2];
#pragma unroll
        for (int j = 0; j < 4; j++)
#pragma unroll
            for (int kk = 0; kk < 2; kk++) {
                const int r = wn * 64 + j * 16 + cl;
                const int p = (kk * 4 + g) ^ (r & 7);
                bfr[j][kk] = *reinterpret_cast<const bf16x8*>(Bb + (p & 1) * 4096 + r * 32 + (p >> 1) * 8);
            }
#pragma unroll
        for (int kk = 0; kk < 2; kk++) {
            bf16x8 af[2];
#pragma unroll
            for (int i = 0; i < 2; i++) {
                const int r = wm * 32 + i * 16 + cl;
                const int p = (kk * 4 + g) ^ (r & 7);
                af[i] = *reinterpret_cast<const bf16x8*>(Ab + (p & 1) * 4096 + r * 32 + (p >> 1) * 8);
            }
#pragma unroll
            for (int i = 0; i < 2; i++)
#pragma unroll
                for (int j = 0; j < 4; j++)
                    acc[i][j] = __builtin_amdgcn_mfma_f32_16x16x32_bf16(af[i], bfr[j][kk], acc[i][j], 0, 0, 0);
        }
    };

    STAGE(0); STAGE(1); STAGE(2);            // 12 loads in flight

#pragma unroll 1
    for (int t = 0; t < 16; ++t) {
        if (t <= 13)      asm volatile("s_waitcnt vmcnt(8)" ::: "memory");  // tile t landed
        else if (t == 14) asm volatile("s_waitcnt vmcnt(4)" ::: "memory");
        else              asm volatile("s_waitcnt vmcnt(0)" ::: "memory");
        __builtin_amdgcn_s_barrier();        // all waves verified their slices
        asm volatile("" ::: "memory");
        COMPUTE(t % 3);
        asm volatile("" ::: "memory");
        __builtin_amdgcn_s_barrier();        // all waves done reading buf[t%3]
        if (t < 13) STAGE(t + 3);            // overwrite freed buffer; stays in flight
    }

    const int mat = n0 >> 10;        // 0=Q, 1=K, 2=V
    if (mat < 2) {
        float invf[4];
#pragma unroll
        for (int jj = 0; jj < 4; jj++)
            invf[jj] = exp2f(-(float)(jj*8 + (cl >> 1)) * 0.4152410118569779f); // 10000^(-i/32)
#pragma unroll
        for (int i = 0; i < 2; i++) {
#pragma unroll
            for (int jj = 0; jj < 4; jj++) {
                const int gcl = (n0 & 1023) + wn*64 + jj*16 + cl;
                const int hh = gcl >> 6;
                const int dk = jj*16 + cl;
#pragma unroll
                for (int rr = 0; rr < 4; rr++) {
                    int gr = m0 + wm*32 + i*16 + g*4 + rr;
                    int bb = gr >> 11, s = gr & (S_ - 1);
                    float v = acc[i][jj][rr];
                    float p = __shfl_xor(v, 1);      // rope partner (dk^1 = adjacent lane)
                    float ang = (float)s * invf[jj];
                    float sn = __sinf(ang), cs = __cosf(ang);
                    float r = (cl & 1) ? fmaf(v, cs, p * sn) : fmaf(v, cs, -p * sn);
                    long idx;
                    if (mat == 0) {
                        const int lane_p = (s & 15) | (((dk >> 3) & 3) << 4);
                        idx = ((long)(bb*H_ + hh) * 128 + (s >> 4)) * 1024
                            + (dk >> 5) * 512 + lane_p * 8 + (dk & 7);
                        Qf[idx] = f2bf_hw(r);
                    } else {
                        const int vv = s & 63;
                        const int ng = ((vv >> 5) << 1) | ((vv >> 2) & 1);
                        const int slot = ((vv & 31) >> 3) * 4 + (vv & 3);
                        const int lane_p = slot | (((dk >> 3) & 3) << 4);
                        idx = (((long)(bb*H_ + hh) * 32 + (s >> 6)) * 4 + ng) * 1024
                            + (dk >> 5) * 512 + lane_p * 8 + (dk & 7);
                        Kf[idx] = f2bf_hw(r);
                    }
                }
            }
        }
    } else {
#pragma unroll
        for (int i = 0; i < 2; i++) {
#pragma unroll
            for (int jj = 0; jj < 4; jj++) {
                const int gcl = (n0 & 1023) + wn*64 + jj*16 + cl;
                const int hh = gcl >> 6;
                const int sbase = m0 + wm*32 + i*16 + g*4;   // 4 consecutive kv
                const int bb = sbase >> 11, s0l = sbase & (S_ - 1);
                const int lane_p = cl | (((s0l >> 3) & 3) << 4);
                const int e0 = s0l & 7;                      // 0 or 4
                ushort4 o;
                o.x = f2bf_hw(acc[i][jj][0]); o.y = f2bf_hw(acc[i][jj][1]);
                o.z = f2bf_hw(acc[i][jj][2]); o.w = f2bf_hw(acc[i][jj][3]);
                long idx = ((long)(bb*H_ + hh) * 4 + jj) * 32768
                         + (long)(s0l >> 5) * 512 + lane_p * 8 + e0;
                *reinterpret_cast<ushort4*>(Vf + idx) = o;
            }
        }
    }
}

// ---------------- output GEMM  out[M][D] = att[M][D] * Wo[D][D]^T (fp32 out) ------------
#define BM 64
#define BN 128

__global__ __launch_bounds__(256)
void gemm_out(const unsigned short* __restrict__ A, const unsigned short* __restrict__ Bw,
              float* __restrict__ Cf) {
    __shared__ unsigned short As[BM * 64];
    __shared__ unsigned short Bs[BN * 64];
    const int K = D_;
    const int tid  = threadIdx.x;
    const int lane = tid & 63;
    const int wid  = tid >> 6;
    const int wm = wid & 1, wn = wid >> 1;
    const int m0 = blockIdx.y * BM, n0 = blockIdx.x * BN;
    const int g  = lane >> 4, cl = lane & 15;

    f32x4 acc[2][4];
#pragma unroll
    for (int i = 0; i < 2; i++)
#pragma unroll
        for (int j = 0; j < 4; j++) acc[i][j] = f32x4{0.f, 0.f, 0.f, 0.f};

    const int srow = tid >> 3;
    const unsigned short* Asrc[2];
    const unsigned short* Bsrc[4];
#pragma unroll
    for (int q = 0; q < 2; q++) {
        int row = srow + q * 32;
        Asrc[q] = A + (long)(m0 + row) * K + (((tid & 7) ^ (srow & 7)) * 8);
    }
#pragma unroll
    for (int q = 0; q < 4; q++) {
        int row = srow + q * 32;
        Bsrc[q] = Bw + (long)(n0 + row) * K + (((tid & 7) ^ (srow & 7)) * 8);
    }

    for (int k0 = 0; k0 < K; k0 += 64) {
        __syncthreads();
#pragma unroll
        for (int q = 0; q < 2; q++) gld16(Asrc[q] + k0, As + tid * 8 + q * 2048);
#pragma unroll
        for (int q = 0; q < 4; q++) gld16(Bsrc[q] + k0, Bs + tid * 8 + q * 2048);
        __syncthreads();

#pragma unroll
        for (int kk = 0; kk < 2; kk++) {
            bf16x8 af[2], bfr[4];
#pragma unroll
            for (int i = 0; i < 2; i++) {
                int row = wm*32 + i*16 + cl;
                af[i]  = *reinterpret_cast<const bf16x8*>(As + row * 64 + (((kk*4 + g) ^ (cl & 7)) * 8));
            }
#pragma unroll
            for (int j = 0; j < 4; j++) {
                int row = wn*64 + j*16 + cl;
                bfr[j] = *reinterpret_cast<const bf16x8*>(Bs + row * 64 + (((kk*4 + g) ^ (cl & 7)) * 8));
            }
#pragma unroll
            for (int i = 0; i < 2; i++)
#pragma unroll
                for (int j = 0; j < 4; j++)
                    acc[i][j] = __builtin_amdgcn_mfma_f32_16x16x32_bf16(af[i], bfr[j], acc[i][j], 0, 0, 0);
        }
    }

#pragma unroll
    for (int i = 0; i < 2; i++)
#pragma unroll
        for (int j = 0; j < 4; j++)
#pragma unroll
            for (int rr = 0; rr < 4; rr++) {
                int gr = m0 + wm*32 + i*16 + g*4 + rr;
                int gc = n0 + wn*64 + j*16 + cl;
                Cf[(long)gr * D_ + gc] = acc[i][j][rr];
            }
}

// ---------------- causal flash attention v11 -------------------------------------------
// v9 core (permuted-K lane-local P, fixed-max softmax via exp2, 4-wave KV split, paired
// q-tiles) + VALU diet: row-sums via ones-B MFMA (denominator lands in C-layout aligned
// with o — no lp adds, no shuffles), upper clamp dropped (scores at 10 sigma never hit).
#define WQ    32
#define KVBLK 64

__global__ __launch_bounds__(256)
void flash_attn(const unsigned short* __restrict__ Qf, const unsigned short* __restrict__ Kf,
                const unsigned short* __restrict__ Vf, unsigned short* __restrict__ Att) {
    __shared__ __align__(16) char smem[20480];   // combine: [2 slots][2 m][5 frag][64] f32x4
    const int tid  = threadIdx.x;
    const int lane = tid & 63;
    const int wid  = tid >> 6;
    const int g = lane >> 4, cl = lane & 15;
    const int bh = blockIdx.x & (BH_ - 1);
    const int pr = blockIdx.x >> 5;            // 0..31 (pair index)
    const int b = bh >> 4, h = bh & (H_ - 1);

    f32x4* Ol = reinterpret_cast<f32x4*>(smem);

    const unsigned short* Qb = Qf + (long)bh * 131072;
    const unsigned short* Kb = Kf + (long)bh * 131072;
    const unsigned short* Vb = Vf + (long)bh * 131072;

    const float RS = 0.125f * 1.44269504f;     // score -> log2 domain
    const float RB = -10.f * 1.44269504f;

    bf16x8 onesv;
#pragma unroll
    for (int e = 0; e < 8; e++) onesv[e] = (short)0x3F80;   // bf16 1.0

    for (int half = 0; half < 2; half++) {
        const int qt = half ? (S_/WQ - 1 - pr) : pr;
        const int q0 = qt * WQ;
        const int nt = (q0 + WQ + KVBLK - 1) / KVBLK;

        bf16x8 aq[2][2];
#pragma unroll
        for (int m = 0; m < 2; m++)
#pragma unroll
            for (int c = 0; c < 2; c++)
                aq[m][c] = *reinterpret_cast<const bf16x8*>(Qb + ((q0 >> 4) + m) * 1024 + c * 512 + lane * 8);

        f32x4 o[2][4], ol[2];
#pragma unroll
        for (int m = 0; m < 2; m++) {
#pragma unroll
            for (int t = 0; t < 4; t++) o[m][t] = f32x4{0.f, 0.f, 0.f, 0.f};
            ol[m] = f32x4{0.f, 0.f, 0.f, 0.f};
        }

        for (int j = wid; j < nt; j += 4) {
            const int kv0 = j * KVBLK;
            // ---- QK^T with permuted K groups ----
            bf16x8 bk[4][2];
#pragma unroll
            for (int n = 0; n < 4; n++)
#pragma unroll
                for (int c = 0; c < 2; c++)
                    bk[n][c] = *reinterpret_cast<const bf16x8*>(Kb + (j * 4 + n) * 1024 + c * 512 + lane * 8);
            f32x4 sc[2][4];
#pragma unroll
            for (int m = 0; m < 2; m++)
#pragma unroll
                for (int n = 0; n < 4; n++) {
                    f32x4 z = f32x4{0.f, 0.f, 0.f, 0.f};
                    z = __builtin_amdgcn_mfma_f32_16x16x32_bf16(bk[n][0], aq[m][0], z, 0, 0, 0);
                    z = __builtin_amdgcn_mfma_f32_16x16x32_bf16(bk[n][1], aq[m][1], z, 0, 0, 0);
                    sc[m][n] = z;
                }

            // ---- V loads issued early (latency hides under softmax) ----
            bf16x8 bv[4][2];
#pragma unroll
            for (int t = 0; t < 4; t++)
#pragma unroll
                for (int c = 0; c < 2; c++)
                    bv[t][c] = *reinterpret_cast<const bf16x8*>(Vb + (long)t * 32768 + ((kv0 >> 5) + c) * 512 + lane * 8);

            // ---- softmax-lite (p = exp2(s*RS+RB)) + in-register P + PV + ones-rowsum ----
            const bool diag = (kv0 + KVBLK - 1 > q0);
#pragma unroll
            for (int m = 0; m < 2; m++) {
                const int q = q0 + m*16 + cl;
                union { unsigned u[4]; bf16x8 v; } w0, w1;
#pragma unroll
                for (int n = 0; n < 4; n++) {
                    float p4[4];
#pragma unroll
                    for (int rr = 0; rr < 4; rr++) {
                        float pe = __builtin_amdgcn_exp2f(fmaf(sc[m][n][rr], RS, RB));
                        if (diag) {
                            const int kv = kv0 + ((n >> 1) << 5) + (g << 3) + ((n & 1) << 2) + rr;
                            if (kv > q) pe = 0.f;
                        }
                        p4[rr] = pe;
                    }
                    const unsigned lo = packbf2(p4[0], p4[1]);
                    const unsigned hi = packbf2(p4[2], p4[3]);
                    if (n == 0)      { w0.u[0] = lo; w0.u[1] = hi; }
                    else if (n == 1) { w0.u[2] = lo; w0.u[3] = hi; }
                    else if (n == 2) { w1.u[0] = lo; w1.u[1] = hi; }
                    else             { w1.u[2] = lo; w1.u[3] = hi; }
                }
#pragma unroll
                for (int t = 0; t < 4; t++) {
                    o[m][t] = __builtin_amdgcn_mfma_f32_16x16x32_bf16(w0.v, bv[t][0], o[m][t], 0, 0, 0);
                    o[m][t] = __builtin_amdgcn_mfma_f32_16x16x32_bf16(w1.v, bv[t][1], o[m][t], 0, 0, 0);
                }
                ol[m] = __builtin_amdgcn_mfma_f32_16x16x32_bf16(w0.v, onesv, ol[m], 0, 0, 0);
                ol[m] = __builtin_amdgcn_mfma_f32_16x16x32_bf16(w1.v, onesv, ol[m], 0, 0, 0);
            }
        }

        // ---- tree combine of (o, ol) across the 4 waves (additive: fixed max) ----
        // Ol index: ((slot*2 + m)*5 + t)*64 + lane, t=0..3 = o, t=4 = ol.
        __syncthreads();
        if (wid == 1 || wid == 3) {
            const int slot = wid >> 1;
#pragma unroll
            for (int m = 0; m < 2; m++) {
#pragma unroll
                for (int t = 0; t < 4; t++)
                    Ol[((slot*2 + m)*5 + t)*64 + lane] = o[m][t];
                Ol[((slot*2 + m)*5 + 4)*64 + lane] = ol[m];
            }
        }
        __syncthreads();
        if (wid == 0 || wid == 2) {
            const int slot = wid >> 1;
#pragma unroll
            for (int m = 0; m < 2; m++) {
#pragma unroll
                for (int t = 0; t < 4; t++) {
                    f32x4 v = Ol[((slot*2 + m)*5 + t)*64 + lane];
#pragma unroll
                    for (int rr = 0; rr < 4; rr++) o[m][t][rr] += v[rr];
                }
                f32x4 vl = Ol[((slot*2 + m)*5 + 4)*64 + lane];
#pragma unroll
                for (int rr = 0; rr < 4; rr++) ol[m][rr] += vl[rr];
            }
        }
        __syncthreads();
        if (wid == 2) {
#pragma unroll
            for (int m = 0; m < 2; m++) {
#pragma unroll
                for (int t = 0; t < 4; t++)
                    Ol[(m*5 + t)*64 + lane] = o[m][t];
                Ol[(m*5 + 4)*64 + lane] = ol[m];
            }
        }
        __syncthreads();
        if (wid == 0) {
#pragma unroll
            for (int m = 0; m < 2; m++) {
#pragma unroll
                for (int t = 0; t < 4; t++) {
                    f32x4 v = Ol[(m*5 + t)*64 + lane];
#pragma unroll
                    for (int rr = 0; rr < 4; rr++) o[m][t][rr] += v[rr];
                }
                f32x4 vl = Ol[(m*5 + 4)*64 + lane];
#pragma unroll
                for (int rr = 0; rr < 4; rr++) ol[m][rr] += vl[rr];
            }
#pragma unroll
            for (int m = 0; m < 2; m++) {
                float linv[4];
#pragma unroll
                for (int rr = 0; rr < 4; rr++) linv[rr] = 1.0f / ol[m][rr];
#pragma unroll
                for (int t = 0; t < 4; t++)
#pragma unroll
                    for (int rr = 0; rr < 4; rr++) {
                        const int q = q0 + m*16 + g*4 + rr;
                        const int d = t*16 + cl;
                        Att[(long)(b * S_ + q) * D_ + h * DK_ + d] = f2bf_hw(o[m][t][rr] * linv[rr]);
                    }
            }
        }
        __syncthreads();   // combine region reused by next half
    }
}

extern "C" void kernel_launch(void* const* d_in, const int* in_sizes, int n_in,
                              void* d_out, int out_size, void* d_ws, size_t ws_size,
                              hipStream_t stream) {
    const float* x  = (const float*)d_in[0];
    const float* Wq = (const float*)d_in[1];
    const float* Wk = (const float*)d_in[2];
    const float* Wv = (const float*)d_in[3];
    const float* Wo = (const float*)d_in[4];
    float* out = (float*)d_out;

    char* ws = (char*)d_ws;
    unsigned short* xb  = (unsigned short*)(ws);
    unsigned short* att = xb;                               // alias: x dead after QKV proj
    unsigned short* WqB = (unsigned short*)(ws + (8  << 20));  // Wq,Wk,Wv contiguous (6 MB)
    unsigned short* WkB = (unsigned short*)(ws + (10 << 20));
    unsigned short* WvB = (unsigned short*)(ws + (12 << 20));
    unsigned short* WoB = (unsigned short*)(ws + (14 << 20));
    unsigned short* Qf  = (unsigned short*)(ws + (16 << 20));
    unsigned short* Kf  = (unsigned short*)(ws + (24 << 20));
    unsigned short* Vf  = (unsigned short*)(ws + (32 << 20));

    const int nx = B_ * S_ * D_;
    cast_f32_to_bf16<<<4096, 256, 0, stream>>>(x, xb, nx);
    cast4_f32_to_bf16<<<dim3(1024, 4), 256, 0, stream>>>(Wq, Wk, Wv, Wo, WqB, WkB, WvB, WoB);

    dim3 qkvgrid(3 * D_ / BNQ, M_ / BMQ);   // (24, 32) = 768 blocks, 512 threads each
    gemm_qkv<<<qkvgrid, 512, 0, stream>>>(xb, WqB, Qf, Kf, Vf);

    flash_attn<<<(S_/WQ/2) * BH_, 256, 0, stream>>>(Qf, Kf, Vf, att);  // 1024 uniform blocks

    dim3 ogrid(D_ / BN, M_ / BM);           // (8, 64) = 512 blocks
    gemm_out<<<ogrid, 256, 0, stream>>>(att, WoB, out);
}

// Round 16
// 116.502 us; speedup vs baseline: 1.0998x; 1.0998x over previous
//
#include <hip/hip_runtime.h>
#include <hip/hip_bf16.h>

// Problem constants
#define B_  2
#define S_  2048
#define D_  1024
#define H_  16
#define DK_ 64
#define BH_ (B_*H_)     // 32
#define M_  (B_*S_)     // 4096

typedef __attribute__((ext_vector_type(8))) short bf16x8;
typedef __attribute__((ext_vector_type(4))) float f32x4;

__device__ inline unsigned short f2bf(float f) {   // manual RNE
    unsigned u = __float_as_uint(f);
    u += 0x7fffu + ((u >> 16) & 1u);
    return (unsigned short)(u >> 16);
}
__device__ inline unsigned short f2bf_hw(float f) {
    __hip_bfloat16 h = __float2bfloat16(f);
    return *reinterpret_cast<unsigned short*>(&h);
}
__device__ inline unsigned packbf2(float lo, float hi) {
    return (unsigned)f2bf_hw(lo) | ((unsigned)f2bf_hw(hi) << 16);
}

// async 16B global->LDS (LDS dest must be linear: uniform base + lane*16)
__device__ inline void gld16(const void* g, void* l) {
    __builtin_amdgcn_global_load_lds(
        (const __attribute__((address_space(1))) unsigned int*)g,
        (__attribute__((address_space(3))) unsigned int*)l, 16, 0, 0);
}

// T1: bijective XCD swizzle (requires nwg % 8 == 0).  Measured null (R14) but harmless;
// kept to preserve the exact best-measured binary layout.
__device__ inline int xcd_swizzle(int orig, int nwg) {
    const int q = nwg >> 3;
    return (orig & 7) * q + (orig >> 3);
}

// ---------------- cast fp32 -> bf16 (x) ----------------
__global__ void cast_f32_to_bf16(const float* __restrict__ src,
                                 unsigned short* __restrict__ dst, int n) {
    int i = (blockIdx.x * blockDim.x + threadIdx.x) * 4;
    int stride = gridDim.x * blockDim.x * 4;
    for (int j = i; j < n; j += stride) {
        float4 v = *reinterpret_cast<const float4*>(src + j);
        ushort4 o;
        o.x = f2bf(v.x); o.y = f2bf(v.y); o.z = f2bf(v.z); o.w = f2bf(v.w);
        *reinterpret_cast<ushort4*>(dst + j) = o;
    }
}

// ---------------- 4 weight casts in one launch ----------------
__global__ void cast4_f32_to_bf16(const float* __restrict__ s0, const float* __restrict__ s1,
                                  const float* __restrict__ s2, const float* __restrict__ s3,
                                  unsigned short* __restrict__ d0, unsigned short* __restrict__ d1,
                                  unsigned short* __restrict__ d2, unsigned short* __restrict__ d3) {
    const float* s; unsigned short* d;
    switch (blockIdx.y) {
        case 0: s = s0; d = d0; break;
        case 1: s = s1; d = d1; break;
        case 2: s = s2; d = d2; break;
        default: s = s3; d = d3; break;
    }
    int j = (blockIdx.x * blockDim.x + threadIdx.x) * 4;
    float4 v = *reinterpret_cast<const float4*>(s + j);
    ushort4 o;
    o.x = f2bf(v.x); o.y = f2bf(v.y); o.z = f2bf(v.z); o.w = f2bf(v.w);
    *reinterpret_cast<ushort4*>(d + j) = o;
}

// ---------------- fused QKV projection + RoPE + fragment-major store -------------------
// 128x128 tile, BK=64, single-buffered, gld16 + both-sides XOR swizzle (0 bank conflicts
// measured), T1 XCD swizzle.  Plateau: ~48 us across 7 structural variants (R9-R15).
// Q:  Qf[bh][s/16][c=dk/32][lane][e]           lane=(s&15)|((dk>>3)&3)<<4, e=dk&7
// K:  Kf[bh][kv/64][n][c][lane][e]  PERMUTED: row v=kv&63 -> n=(v>>5)*2|((v>>2)&1),
//     slot=((v&31)>>3)*4+(v&3); lane=slot|((dk>>3)&3)<<4.  (QK mfma n then yields
//     lane-local P in exactly PV A-fragment order -> flash needs NO LDS for P.)
// V:  Vf[bh][dk/16][kv/32][lane][e]            lane=(dk&15)|((kv>>3)&3)<<4, e=kv&7
#define BMQ 128
#define BNQ 128

__global__ __launch_bounds__(256)
void gemm_qkv(const unsigned short* __restrict__ A, const unsigned short* __restrict__ Wcat,
              unsigned short* __restrict__ Qf, unsigned short* __restrict__ Kf,
              unsigned short* __restrict__ Vf) {
    __shared__ unsigned short As[BMQ * 64];   // 16 KB
    __shared__ unsigned short Bs[BNQ * 64];   // 16 KB
    const int K = D_;
    const int tid  = threadIdx.x;
    const int lane = tid & 63;
    const int wid  = tid >> 6;
    const int wm = wid & 1, wn = wid >> 1;          // wave tile 64x64
    const int nbx = 3 * D_ / BNQ;                   // 24
    const int wg  = xcd_swizzle((int)(blockIdx.y * nbx + blockIdx.x), nbx * (M_ / BMQ));
    const int m0 = (wg / nbx) * BMQ, n0 = (wg % nbx) * BNQ;
    const int g  = lane >> 4, cl = lane & 15;

    f32x4 acc[4][4];
#pragma unroll
    for (int i = 0; i < 4; i++)
#pragma unroll
        for (int j = 0; j < 4; j++) acc[i][j] = f32x4{0.f, 0.f, 0.f, 0.f};

    const int srow = tid >> 3;
    const unsigned short* Asrc[4];
    const unsigned short* Bsrc[4];
#pragma unroll
    for (int q = 0; q < 4; q++) {
        int row = srow + q * 32;
        Asrc[q] = A    + (long)(m0 + row) * K + (((tid & 7) ^ (srow & 7)) * 8);
        Bsrc[q] = Wcat + (long)(n0 + row) * K + (((tid & 7) ^ (srow & 7)) * 8);
    }

    for (int k0 = 0; k0 < K; k0 += 64) {
        __syncthreads();
#pragma unroll
        for (int q = 0; q < 4; q++) gld16(Asrc[q] + k0, As + tid * 8 + q * 2048);
#pragma unroll
        for (int q = 0; q < 4; q++) gld16(Bsrc[q] + k0, Bs + tid * 8 + q * 2048);
        __syncthreads();

#pragma unroll
        for (int kk = 0; kk < 2; kk++) {
            bf16x8 af[4], bfr[4];
#pragma unroll
            for (int i = 0; i < 4; i++) {
                int row = wm*64 + i*16 + cl;
                af[i]  = *reinterpret_cast<const bf16x8*>(As + row * 64 + (((kk*4 + g) ^ (cl & 7)) * 8));
            }
#pragma unroll
            for (int j = 0; j < 4; j++) {
                int row = wn*64 + j*16 + cl;
                bfr[j] = *reinterpret_cast<const bf16x8*>(Bs + row * 64 + (((kk*4 + g) ^ (cl & 7)) * 8));
            }
#pragma unroll
            for (int i = 0; i < 4; i++)
#pragma unroll
                for (int j = 0; j < 4; j++)
                    acc[i][j] = __builtin_amdgcn_mfma_f32_16x16x32_bf16(af[i], bfr[j], acc[i][j], 0, 0, 0);
        }
    }

    const int mat = n0 >> 10;        // 0=Q, 1=K, 2=V
    if (mat < 2) {
        float invf[4];
#pragma unroll
        for (int jj = 0; jj < 4; jj++)
            invf[jj] = exp2f(-(float)(jj*8 + (cl >> 1)) * 0.4152410118569779f); // 10000^(-i/32)
#pragma unroll
        for (int i = 0; i < 4; i++) {
#pragma unroll
            for (int jj = 0; jj < 4; jj++) {
                const int gcl = (n0 & 1023) + wn*64 + jj*16 + cl;
                const int hh = gcl >> 6;
                const int dk = jj*16 + cl;
#pragma unroll
                for (int rr = 0; rr < 4; rr++) {
                    int gr = m0 + wm*64 + i*16 + g*4 + rr;
                    int bb = gr >> 11, s = gr & (S_ - 1);
                    float v = acc[i][jj][rr];
                    float p = __shfl_xor(v, 1);      // rope partner (dk^1 = adjacent lane)
                    float ang = (float)s * invf[jj];
                    float sn = __sinf(ang), cs = __cosf(ang);
                    float r = (cl & 1) ? fmaf(v, cs, p * sn) : fmaf(v, cs, -p * sn);
                    long idx;
                    if (mat == 0) {
                        const int lane_p = (s & 15) | (((dk >> 3) & 3) << 4);
                        idx = ((long)(bb*H_ + hh) * 128 + (s >> 4)) * 1024
                            + (dk >> 5) * 512 + lane_p * 8 + (dk & 7);
                        Qf[idx] = f2bf_hw(r);
                    } else {
                        const int vv = s & 63;
                        const int ng = ((vv >> 5) << 1) | ((vv >> 2) & 1);
                        const int slot = ((vv & 31) >> 3) * 4 + (vv & 3);
                        const int lane_p = slot | (((dk >> 3) & 3) << 4);
                        idx = (((long)(bb*H_ + hh) * 32 + (s >> 6)) * 4 + ng) * 1024
                            + (dk >> 5) * 512 + lane_p * 8 + (dk & 7);
                        Kf[idx] = f2bf_hw(r);
                    }
                }
            }
        }
    } else {
#pragma unroll
        for (int i = 0; i < 4; i++) {
#pragma unroll
            for (int jj = 0; jj < 4; jj++) {
                const int gcl = (n0 & 1023) + wn*64 + jj*16 + cl;
                const int hh = gcl >> 6;
                const int sbase = m0 + wm*64 + i*16 + g*4;   // 4 consecutive kv
                const int bb = sbase >> 11, s0l = sbase & (S_ - 1);
                const int lane_p = cl | (((s0l >> 3) & 3) << 4);
                const int e0 = s0l & 7;                      // 0 or 4
                ushort4 o;
                o.x = f2bf_hw(acc[i][jj][0]); o.y = f2bf_hw(acc[i][jj][1]);
                o.z = f2bf_hw(acc[i][jj][2]); o.w = f2bf_hw(acc[i][jj][3]);
                long idx = ((long)(bb*H_ + hh) * 4 + jj) * 32768
                         + (long)(s0l >> 5) * 512 + lane_p * 8 + e0;
                *reinterpret_cast<ushort4*>(Vf + idx) = o;
            }
        }
    }
}

// ---------------- output GEMM  out[M][D] = att[M][D] * Wo[D][D]^T (fp32 out) ------------
#define BM 64
#define BN 128

__global__ __launch_bounds__(256)
void gemm_out(const unsigned short* __restrict__ A, const unsigned short* __restrict__ Bw,
              float* __restrict__ Cf) {
    __shared__ unsigned short As[BM * 64];
    __shared__ unsigned short Bs[BN * 64];
    const int K = D_;
    const int tid  = threadIdx.x;
    const int lane = tid & 63;
    const int wid  = tid >> 6;
    const int wm = wid & 1, wn = wid >> 1;
    const int nbx = D_ / BN;                         // 8
    const int wg  = xcd_swizzle((int)(blockIdx.y * nbx + blockIdx.x), nbx * (M_ / BM));
    const int m0 = (wg / nbx) * BM, n0 = (wg % nbx) * BN;
    const int g  = lane >> 4, cl = lane & 15;

    f32x4 acc[2][4];
#pragma unroll
    for (int i = 0; i < 2; i++)
#pragma unroll
        for (int j = 0; j < 4; j++) acc[i][j] = f32x4{0.f, 0.f, 0.f, 0.f};

    const int srow = tid >> 3;
    const unsigned short* Asrc[2];
    const unsigned short* Bsrc[4];
#pragma unroll
    for (int q = 0; q < 2; q++) {
        int row = srow + q * 32;
        Asrc[q] = A + (long)(m0 + row) * K + (((tid & 7) ^ (srow & 7)) * 8);
    }
#pragma unroll
    for (int q = 0; q < 4; q++) {
        int row = srow + q * 32;
        Bsrc[q] = Bw + (long)(n0 + row) * K + (((tid & 7) ^ (srow & 7)) * 8);
    }

    for (int k0 = 0; k0 < K; k0 += 64) {
        __syncthreads();
#pragma unroll
        for (int q = 0; q < 2; q++) gld16(Asrc[q] + k0, As + tid * 8 + q * 2048);
#pragma unroll
        for (int q = 0; q < 4; q++) gld16(Bsrc[q] + k0, Bs + tid * 8 + q * 2048);
        __syncthreads();

#pragma unroll
        for (int kk = 0; kk < 2; kk++) {
            bf16x8 af[2], bfr[4];
#pragma unroll
            for (int i = 0; i < 2; i++) {
                int row = wm*32 + i*16 + cl;
                af[i]  = *reinterpret_cast<const bf16x8*>(As + row * 64 + (((kk*4 + g) ^ (cl & 7)) * 8));
            }
#pragma unroll
            for (int j = 0; j < 4; j++) {
                int row = wn*64 + j*16 + cl;
                bfr[j] = *reinterpret_cast<const bf16x8*>(Bs + row * 64 + (((kk*4 + g) ^ (cl & 7)) * 8));
            }
#pragma unroll
            for (int i = 0; i < 2; i++)
#pragma unroll
                for (int j = 0; j < 4; j++)
                    acc[i][j] = __builtin_amdgcn_mfma_f32_16x16x32_bf16(af[i], bfr[j], acc[i][j], 0, 0, 0);
        }
    }

#pragma unroll
    for (int i = 0; i < 2; i++)
#pragma unroll
        for (int j = 0; j < 4; j++)
#pragma unroll
            for (int rr = 0; rr < 4; rr++) {
                int gr = m0 + wm*32 + i*16 + g*4 + rr;
                int gc = n0 + wn*64 + j*16 + cl;
                Cf[(long)gr * D_ + gc] = acc[i][j][rr];
            }
}

// ---------------- causal flash attention v9 (best measured: 47.5 us) --------------------
// Permuted-K QK^T -> lane-local P (no LDS, no cross-lane).  Fixed-max softmax via exp2
// (reference clips scores to +-10 after 1/8 scale -> constant max is exact).  4-wave KV
// split + paired q-tiles (uniform 33-tile blocks).  V loads issued early.
#define WQ    32
#define KVBLK 64

__global__ __launch_bounds__(256)
void flash_attn(const unsigned short* __restrict__ Qf, const unsigned short* __restrict__ Kf,
                const unsigned short* __restrict__ Vf, unsigned short* __restrict__ Att) {
    __shared__ __align__(16) char smem[17408];   // combine: Ol 16KB + Ll 1KB
    const int tid  = threadIdx.x;
    const int lane = tid & 63;
    const int wid  = tid >> 6;
    const int g = lane >> 4, cl = lane & 15;
    const int bh = blockIdx.x & (BH_ - 1);
    const int pr = blockIdx.x >> 5;            // 0..31 (pair index)
    const int b = bh >> 4, h = bh & (H_ - 1);

    f32x4* Ol = reinterpret_cast<f32x4*>(smem);
    float* Ll = reinterpret_cast<float*>(smem + 16384);

    const unsigned short* Qb = Qf + (long)bh * 131072;
    const unsigned short* Kb = Kf + (long)bh * 131072;
    const unsigned short* Vb = Vf + (long)bh * 131072;

    const float RS = 0.125f * 1.44269504f;     // score -> log2 domain
    const float RB = -10.f * 1.44269504f;

    for (int half = 0; half < 2; half++) {
        const int qt = half ? (S_/WQ - 1 - pr) : pr;
        const int q0 = qt * WQ;
        const int nt = (q0 + WQ + KVBLK - 1) / KVBLK;

        bf16x8 aq[2][2];
#pragma unroll
        for (int m = 0; m < 2; m++)
#pragma unroll
            for (int c = 0; c < 2; c++)
                aq[m][c] = *reinterpret_cast<const bf16x8*>(Qb + ((q0 >> 4) + m) * 1024 + c * 512 + lane * 8);

        f32x4 o[2][4];
#pragma unroll
        for (int m = 0; m < 2; m++)
#pragma unroll
            for (int t = 0; t < 4; t++) o[m][t] = f32x4{0.f, 0.f, 0.f, 0.f};
        float lp[2] = {0.f, 0.f};

        for (int j = wid; j < nt; j += 4) {
            const int kv0 = j * KVBLK;
            // ---- QK^T with permuted K groups ----
            bf16x8 bk[4][2];
#pragma unroll
            for (int n = 0; n < 4; n++)
#pragma unroll
                for (int c = 0; c < 2; c++)
                    bk[n][c] = *reinterpret_cast<const bf16x8*>(Kb + (j * 4 + n) * 1024 + c * 512 + lane * 8);
            f32x4 sc[2][4];
#pragma unroll
            for (int m = 0; m < 2; m++)
#pragma unroll
                for (int n = 0; n < 4; n++) {
                    f32x4 z = f32x4{0.f, 0.f, 0.f, 0.f};
                    z = __builtin_amdgcn_mfma_f32_16x16x32_bf16(bk[n][0], aq[m][0], z, 0, 0, 0);
                    z = __builtin_amdgcn_mfma_f32_16x16x32_bf16(bk[n][1], aq[m][1], z, 0, 0, 0);
                    sc[m][n] = z;
                }

            // ---- V loads issued early (latency hides under softmax) ----
            bf16x8 bv[4][2];
#pragma unroll
            for (int t = 0; t < 4; t++)
#pragma unroll
                for (int c = 0; c < 2; c++)
                    bv[t][c] = *reinterpret_cast<const bf16x8*>(Vb + (long)t * 32768 + ((kv0 >> 5) + c) * 512 + lane * 8);

            // ---- softmax-lite (p = exp2(min(s*RS+RB, 0))) + in-register P + PV ----
            const bool diag = (kv0 + KVBLK - 1 > q0);
#pragma unroll
            for (int m = 0; m < 2; m++) {
                const int q = q0 + m*16 + cl;
                union { unsigned u[4]; bf16x8 v; } w0, w1;
#pragma unroll
                for (int n = 0; n < 4; n++) {
                    float p4[4];
#pragma unroll
                    for (int rr = 0; rr < 4; rr++) {
                        float u2 = fminf(fmaf(sc[m][n][rr], RS, RB), 0.f);
                        float pe = __builtin_amdgcn_exp2f(u2);
                        if (diag) {
                            const int kv = kv0 + ((n >> 1) << 5) + (g << 3) + ((n & 1) << 2) + rr;
                            if (kv > q) pe = 0.f;
                        }
                        p4[rr] = pe;
                    }
                    lp[m] += (p4[0] + p4[1]) + (p4[2] + p4[3]);
                    const unsigned lo = packbf2(p4[0], p4[1]);
                    const unsigned hi = packbf2(p4[2], p4[3]);
                    if (n == 0)      { w0.u[0] = lo; w0.u[1] = hi; }
                    else if (n == 1) { w0.u[2] = lo; w0.u[3] = hi; }
                    else if (n == 2) { w1.u[0] = lo; w1.u[1] = hi; }
                    else             { w1.u[2] = lo; w1.u[3] = hi; }
                }
#pragma unroll
                for (int t = 0; t < 4; t++) {
                    o[m][t] = __builtin_amdgcn_mfma_f32_16x16x32_bf16(w0.v, bv[t][0], o[m][t], 0, 0, 0);
                    o[m][t] = __builtin_amdgcn_mfma_f32_16x16x32_bf16(w1.v, bv[t][1], o[m][t], 0, 0, 0);
                }
            }
        }

        // ---- tree combine of (o, lp) across the 4 waves (additive: fixed max) ----
        __syncthreads();
        if (wid == 1 || wid == 3) {
            const int slot = wid >> 1;
#pragma unroll
            for (int m = 0; m < 2; m++) {
#pragma unroll
                for (int t = 0; t < 4; t++)
                    Ol[(slot*8 + m*4 + t)*64 + lane] = o[m][t];
                Ll[(slot*2 + m)*64 + lane] = lp[m];
            }
        }
        __syncthreads();
        if (wid == 0 || wid == 2) {
            const int slot = wid >> 1;
#pragma unroll
            for (int m = 0; m < 2; m++) {
#pragma unroll
                for (int t = 0; t < 4; t++) {
                    f32x4 v = Ol[(slot*8 + m*4 + t)*64 + lane];
#pragma unroll
                    for (int rr = 0; rr < 4; rr++) o[m][t][rr] += v[rr];
                }
                lp[m] += Ll[(slot*2 + m)*64 + lane];
            }
        }
        __syncthreads();
        if (wid == 2) {
#pragma unroll
            for (int m = 0; m < 2; m++) {
#pragma unroll
                for (int t = 0; t < 4; t++)
                    Ol[(m*4 + t)*64 + lane] = o[m][t];
                Ll[m*64 + lane] = lp[m];
            }
        }
        __syncthreads();
        if (wid == 0) {
#pragma unroll
            for (int m = 0; m < 2; m++) {
#pragma unroll
                for (int t = 0; t < 4; t++) {
                    f32x4 v = Ol[(m*4 + t)*64 + lane];
#pragma unroll
                    for (int rr = 0; rr < 4; rr++) o[m][t][rr] += v[rr];
                }
                lp[m] += Ll[m*64 + lane];
                lp[m] += __shfl_xor(lp[m], 16);
                lp[m] += __shfl_xor(lp[m], 32);
            }
            float linv[2][4];
#pragma unroll
            for (int m = 0; m < 2; m++)
#pragma unroll
                for (int rr = 0; rr < 4; rr++)
                    linv[m][rr] = 1.0f / __shfl(lp[m], g*4 + rr);
#pragma unroll
            for (int m = 0; m < 2; m++)
#pragma unroll
                for (int t = 0; t < 4; t++)
#pragma unroll
                    for (int rr = 0; rr < 4; rr++) {
                        const int q = q0 + m*16 + g*4 + rr;
                        const int d = t*16 + cl;
                        Att[(long)(b * S_ + q) * D_ + h * DK_ + d] = f2bf_hw(o[m][t][rr] * linv[m][rr]);
                    }
        }
        __syncthreads();   // combine region reused by next half
    }
}

extern "C" void kernel_launch(void* const* d_in, const int* in_sizes, int n_in,
                              void* d_out, int out_size, void* d_ws, size_t ws_size,
                              hipStream_t stream) {
    const float* x  = (const float*)d_in[0];
    const float* Wq = (const float*)d_in[1];
    const float* Wk = (const float*)d_in[2];
    const float* Wv = (const float*)d_in[3];
    const float* Wo = (const float*)d_in[4];
    float* out = (float*)d_out;

    char* ws = (char*)d_ws;
    unsigned short* xb  = (unsigned short*)(ws);
    unsigned short* att = xb;                               // alias: x dead after QKV proj
    unsigned short* WqB = (unsigned short*)(ws + (8  << 20));  // Wq,Wk,Wv contiguous (6 MB)
    unsigned short* WkB = (unsigned short*)(ws + (10 << 20));
    unsigned short* WvB = (unsigned short*)(ws + (12 << 20));
    unsigned short* WoB = (unsigned short*)(ws + (14 << 20));
    unsigned short* Qf  = (unsigned short*)(ws + (16 << 20));
    unsigned short* Kf  = (unsigned short*)(ws + (24 << 20));
    unsigned short* Vf  = (unsigned short*)(ws + (32 << 20));

    const int nx = B_ * S_ * D_;
    cast_f32_to_bf16<<<4096, 256, 0, stream>>>(x, xb, nx);
    cast4_f32_to_bf16<<<dim3(1024, 4), 256, 0, stream>>>(Wq, Wk, Wv, Wo, WqB, WkB, WvB, WoB);

    dim3 qkvgrid(3 * D_ / BNQ, M_ / BMQ);   // (24, 32) = 768 blocks
    gemm_qkv<<<qkvgrid, 256, 0, stream>>>(xb, WqB, Qf, Kf, Vf);

    flash_attn<<<(S_/WQ/2) * BH_, 256, 0, stream>>>(Qf, Kf, Vf, att);  // 1024 uniform blocks

    dim3 ogrid(D_ / BN, M_ / BM);           // (8, 64) = 512 blocks
    gemm_out<<<ogrid, 256, 0, stream>>>(att, WoB, out);
}